// Round 2
// baseline (533.608 us; speedup 1.0000x reference)
//
#include <hip/hip_runtime.h>
#include <stdint.h>

typedef _Float16 f16;
typedef __attribute__((ext_vector_type(8))) _Float16 half8;
typedef __attribute__((ext_vector_type(8))) short short8;
typedef __attribute__((ext_vector_type(4))) float f32x4;

#define NPOS 4096
#define CCH  256
#define OQK  64
#define BATCH 2

__device__ __forceinline__ float bf2f(short u) {
    union { uint32_t i; float f; } c;
    c.i = ((uint32_t)(uint16_t)u) << 16;
    return c.f;
}
__device__ __forceinline__ short f2bf(float f) {
    union { float f; uint32_t i; } c; c.f = f;
    uint32_t lsb = (c.i >> 16) & 1u;
    c.i += 0x7FFFu + lsb;
    return (short)(c.i >> 16);
}

// Deterministic dtype sniff: mask values are exactly {0.0,1.0}.
// fp32 words: 0x00000000 / 0x3F800000 -> low16 always 0x0000.
// bf16 pairs: low16 = even-index element in {0x0000, 0x3F80}.
// Any low16 == 0x3F80 among 64 words => bf16 (P_false ~ 2^-64).
__device__ __forceinline__ bool detect_bf16(const uint32_t* mw) {
    int hits = 0;
    #pragma unroll
    for (int i = 0; i < 64; ++i) hits += ((mw[i] & 0xFFFFu) == 0x3F80u) ? 1 : 0;
    return hits != 0;
}

__device__ __forceinline__ void load8(const void* base, size_t e0, bool bf, float* v) {
    if (bf) {
        short8 s = *(const short8*)((const short*)base + e0);
        #pragma unroll
        for (int j = 0; j < 8; ++j) v[j] = bf2f(s[j]);
    } else {
        const float* fp = (const float*)base + e0;
        float4 a = *(const float4*)fp;
        float4 b = *(const float4*)(fp + 4);
        v[0] = a.x; v[1] = a.y; v[2] = a.z; v[3] = a.w;
        v[4] = b.x; v[5] = b.y; v[6] = b.z; v[7] = b.w;
    }
}
__device__ __forceinline__ float load1(const void* base, int i, bool bf) {
    return bf ? bf2f(((const short*)base)[i]) : ((const float*)base)[i];
}

// ---------------------------------------------------------------------------
// Canonicalize all inputs into workspace:
//   x -> xh (f16) + xf (f32); mask -> maskf (f32);
//   weights -> w{1,2}qk (64,256 f16: rows 0-31 wq, 32-63 wk), w{1,2}v (256,256 f16),
//   biases -> b{1,2}[320] f16 (q,k,v); gammas -> gam[2] f32.
// grid = 1109 blocks x 256.
// ---------------------------------------------------------------------------
__global__ __launch_bounds__(256) void convert_inputs(
    const void* __restrict__ x, const uint32_t* __restrict__ mask_raw,
    const void* __restrict__ w1q, const void* __restrict__ w1k, const void* __restrict__ w1v_,
    const void* __restrict__ b1q, const void* __restrict__ b1k, const void* __restrict__ b1v_,
    const void* __restrict__ g1,
    const void* __restrict__ w2q, const void* __restrict__ w2k, const void* __restrict__ w2v_,
    const void* __restrict__ b2q, const void* __restrict__ b2k, const void* __restrict__ b2v_,
    const void* __restrict__ g2,
    f16* __restrict__ xh, float* __restrict__ xf, float* __restrict__ maskf,
    f16* __restrict__ w1qk, f16* __restrict__ w1vm, f16* __restrict__ b1,
    f16* __restrict__ w2qk, f16* __restrict__ w2vm, f16* __restrict__ b2,
    float* __restrict__ gam)
{
    const bool bf = detect_bf16(mask_raw);
    const int blk = blockIdx.x, tid = threadIdx.x;
    float v[8];
    if (blk < 1024) {                       // x: 2,097,152 elements
        const size_t e0 = ((size_t)blk * 256 + tid) * 8;
        load8(x, e0, bf, v);
        half8 h;
        #pragma unroll
        for (int j = 0; j < 8; ++j) h[j] = (f16)v[j];
        *(half8*)(xh + e0) = h;
        float4 f0 = {v[0], v[1], v[2], v[3]}, f1 = {v[4], v[5], v[6], v[7]};
        *(float4*)(xf + e0) = f0;
        *(float4*)(xf + e0 + 4) = f1;
    } else if (blk < 1028) {                // mask: 8192 elements
        const size_t e0 = ((size_t)(blk - 1024) * 256 + tid) * 8;
        load8(mask_raw, e0, bf, v);
        float4 f0 = {v[0], v[1], v[2], v[3]}, f1 = {v[4], v[5], v[6], v[7]};
        *(float4*)(maskf + e0) = f0;
        *(float4*)(maskf + e0 + 4) = f1;
    } else if (blk < 1036) {                // w1qk: 16384 elements
        const size_t g = ((size_t)(blk - 1028) * 256 + tid) * 8;
        const int o = (int)(g >> 8), cc = (int)(g & 255);
        const void* src = (o < 32) ? w1q : w1k;
        const size_t se = (size_t)((o < 32) ? o : o - 32) * 256 + cc;
        load8(src, se, bf, v);
        half8 h;
        #pragma unroll
        for (int j = 0; j < 8; ++j) h[j] = (f16)v[j];
        *(half8*)(w1qk + g) = h;
    } else if (blk < 1068) {                // w1v: 65536 elements
        const size_t g = ((size_t)(blk - 1036) * 256 + tid) * 8;
        load8(w1v_, g, bf, v);
        half8 h;
        #pragma unroll
        for (int j = 0; j < 8; ++j) h[j] = (f16)v[j];
        *(half8*)(w1vm + g) = h;
    } else if (blk < 1076) {                // w2qk
        const size_t g = ((size_t)(blk - 1068) * 256 + tid) * 8;
        const int o = (int)(g >> 8), cc = (int)(g & 255);
        const void* src = (o < 32) ? w2q : w2k;
        const size_t se = (size_t)((o < 32) ? o : o - 32) * 256 + cc;
        load8(src, se, bf, v);
        half8 h;
        #pragma unroll
        for (int j = 0; j < 8; ++j) h[j] = (f16)v[j];
        *(half8*)(w2qk + g) = h;
    } else if (blk < 1108) {                // w2v
        const size_t g = ((size_t)(blk - 1076) * 256 + tid) * 8;
        load8(w2v_, g, bf, v);
        half8 h;
        #pragma unroll
        for (int j = 0; j < 8; ++j) h[j] = (f16)v[j];
        *(half8*)(w2vm + g) = h;
    } else {                                // biases + gammas
        for (int i = tid; i < 320; i += 256) {
            const void* s1 = (i < 32) ? b1q : (i < 64) ? b1k : b1v_;
            const void* s2 = (i < 32) ? b2q : (i < 64) ? b2k : b2v_;
            const int ii = (i < 32) ? i : (i < 64) ? i - 32 : i - 64;
            b1[i] = (f16)load1(s1, ii, bf);
            b2[i] = (f16)load1(s2, ii, bf);
        }
        if (tid == 0) {
            gam[0] = load1(g1, 0, bf);
            gam[1] = load1(g2, 0, bf);
        }
    }
}

// ---------------------------------------------------------------------------
// Fused 1x1 conv producing q,k (packed (B,N,64)) and v ((B,C,N)) in fp16.
// use_mask: q gets mask[n], k/v get (1-mask[n]); bias added unmasked
// (linearity: conv(m*x) = m*(Wx) + b).
// grid = (N/64, B), 256 threads. LDS x-tile transposed [n][c], XOR-swizzled.
// ---------------------------------------------------------------------------
__global__ __launch_bounds__(256) void conv_qkv(
    const f16* __restrict__ xin,   // (B,C,N) f16
    const f16* __restrict__ wqk,   // (64,256)
    const f16* __restrict__ wvm,   // (256,256)
    const f16* __restrict__ bias,  // (320)
    const float* __restrict__ maskf, int use_mask,
    f16* __restrict__ qkout,       // (B,N,64)
    f16* __restrict__ vout)        // (B,C,N)
{
    const int b    = blockIdx.y;
    const int n0   = blockIdx.x * 64;
    const int tid  = threadIdx.x;
    const int lane = tid & 63;
    const int w    = tid >> 6;
    const int lo   = lane & 15;
    const int hi   = lane >> 4;

    __shared__ f16 xt[64 * 256];   // [n][c], 32 KB

    {
        const int nc = tid & 7;
        const int cg = tid >> 3;
        #pragma unroll
        for (int it = 0; it < 8; ++it) {
            const int c = cg + 32 * it;
            const size_t off = ((size_t)b * CCH + c) * NPOS + n0 + nc * 8;
            half8 vv = *(const half8*)(xin + off);
            #pragma unroll
            for (int j = 0; j < 8; ++j) {
                const int n = nc * 8 + j;
                int byte = n * 512 + c * 2;
                byte ^= ((n & 7) << 4);
                *(f16*)((char*)xt + byte) = vv[j];
            }
        }
    }
    __syncthreads();

    const f32x4 z = {0.f, 0.f, 0.f, 0.f};
    f32x4 acc_qk[4];
    f32x4 acc_v[4][4];
    #pragma unroll
    for (int i = 0; i < 4; ++i) {
        acc_qk[i] = z;
        #pragma unroll
        for (int j = 0; j < 4; ++j) acc_v[i][j] = z;
    }

    #pragma unroll 1
    for (int ks = 0; ks < 8; ++ks) {
        const int ce = ks * 32 + 8 * hi;
        half8 xfr[4];
        #pragma unroll
        for (int nt = 0; nt < 4; ++nt) {
            const int n = nt * 16 + lo;
            int byte = n * 512 + ce * 2;
            byte ^= ((n & 7) << 4);
            xfr[nt] = *(const half8*)((const char*)xt + byte);
        }
        {
            half8 wf = *(const half8*)(wqk + (size_t)(w * 16 + lo) * 256 + ce);
            #pragma unroll
            for (int nt = 0; nt < 4; ++nt)
                acc_qk[nt] = __builtin_amdgcn_mfma_f32_16x16x32_f16(xfr[nt], wf, acc_qk[nt], 0, 0, 0);
        }
        #pragma unroll
        for (int ot = 0; ot < 4; ++ot) {
            half8 wf = *(const half8*)(wvm + (size_t)(w * 64 + ot * 16 + lo) * 256 + ce);
            #pragma unroll
            for (int nt = 0; nt < 4; ++nt)
                acc_v[ot][nt] = __builtin_amdgcn_mfma_f32_16x16x32_f16(wf, xfr[nt], acc_v[ot][nt], 0, 0, 0);
        }
    }

    {   // qk epilogue: col o = w*16+lo, rows n = nt*16 + 4*hi + r
        const int o = w * 16 + lo;
        const float bb = (float)bias[o];
        #pragma unroll
        for (int nt = 0; nt < 4; ++nt) {
            #pragma unroll
            for (int r = 0; r < 4; ++r) {
                const int n = n0 + nt * 16 + 4 * hi + r;
                float mult = 1.f;
                if (use_mask) {
                    const float mv = maskf[b * NPOS + n];
                    mult = (o < 32) ? mv : (1.f - mv);
                }
                qkout[((size_t)b * NPOS + n) * OQK + o] = (f16)(mult * acc_qk[nt][r] + bb);
            }
        }
    }
    {   // v epilogue: col n = nt*16+lo, rows o = w*64 + ot*16 + 4*hi + r
        float mv_n[4];
        #pragma unroll
        for (int nt = 0; nt < 4; ++nt)
            mv_n[nt] = use_mask ? (1.f - maskf[b * NPOS + n0 + nt * 16 + lo]) : 1.f;
        #pragma unroll
        for (int ot = 0; ot < 4; ++ot) {
            #pragma unroll
            for (int r = 0; r < 4; ++r) {
                const int oc = w * 64 + ot * 16 + 4 * hi + r;
                const float bb = (float)bias[64 + oc];
                #pragma unroll
                for (int nt = 0; nt < 4; ++nt) {
                    const int n = n0 + nt * 16 + lo;
                    vout[((size_t)b * CCH + oc) * NPOS + n] = (f16)(mv_n[nt] * acc_v[ot][nt][r] + bb);
                }
            }
        }
    }
}

// ---------------------------------------------------------------------------
// Flash attention, D=32. grid (N/32, B), 4 waves: slab=w>>1 (16 q-rows),
// chalf=w&1 (128 channels). P relayout via 4KB swizzled LDS.
// Pass 1 fuses x1 = gamma*O + x (writes f16 + f32).
// ---------------------------------------------------------------------------
__global__ __launch_bounds__(256) void attn_fused(
    const f16* __restrict__ qk,      // (B,N,64)
    const f16* __restrict__ vbuf,    // (B,C,N)
    const float* __restrict__ xres,  // (B,C,N) f32 (pass1)
    const float* __restrict__ gamp,
    f16* __restrict__ out_h,         // (B,C,N)
    float* __restrict__ out_f,       // (B,C,N) f32 (pass1)
    int add_residual)
{
    const int b    = blockIdx.y;
    const int q0   = blockIdx.x * 32;
    const int tid  = threadIdx.x;
    const int lane = tid & 63;
    const int w    = tid >> 6;
    const int slab = w >> 1;
    const int chalf= w & 1;
    const int lo   = lane & 15;
    const int hi   = lane >> 4;

    __shared__ f16 p_lds[32 * 64];

    const half8 qfrag = *(const half8*)(qk + ((size_t)b * NPOS + q0 + slab * 16 + lo) * OQK + 8 * hi);

    const f32x4 z = {0.f, 0.f, 0.f, 0.f};
    f32x4 acc[8];
    #pragma unroll
    for (int i = 0; i < 8; ++i) acc[i] = z;
    float m_run[4], l_run[4];
    #pragma unroll
    for (int r = 0; r < 4; ++r) { m_run[r] = -3.0e38f; l_run[r] = 0.f; }

    const f16* kbase = qk + (size_t)b * NPOS * OQK + 32 + 8 * hi;
    const f16* vbase = vbuf + (size_t)b * CCH * NPOS;

    for (int kt = 0; kt < NPOS / 64; ++kt) {
        const int j0 = kt * 64;
        f32x4 s[4];
        #pragma unroll
        for (int jt = 0; jt < 4; ++jt) {
            const half8 kfrag = *(const half8*)(kbase + (size_t)(j0 + jt * 16 + lo) * OQK);
            s[jt] = __builtin_amdgcn_mfma_f32_16x16x32_f16(qfrag, kfrag, z, 0, 0, 0);
        }
        float p[4][4];
        #pragma unroll
        for (int r = 0; r < 4; ++r) {
            float pm = fmaxf(fmaxf(s[0][r], s[1][r]), fmaxf(s[2][r], s[3][r]));
            #pragma unroll
            for (int off = 1; off < 16; off <<= 1)
                pm = fmaxf(pm, __shfl_xor(pm, off, 64));
            const float mnew = fmaxf(m_run[r], pm);
            const float scale = __expf(m_run[r] - mnew);
            float rs = 0.f;
            #pragma unroll
            for (int jt = 0; jt < 4; ++jt) {
                const float pv = __expf(s[jt][r] - mnew);
                p[jt][r] = pv;
                rs += pv;
            }
            #pragma unroll
            for (int off = 1; off < 16; off <<= 1)
                rs += __shfl_xor(rs, off, 64);
            l_run[r] = l_run[r] * scale + rs;
            m_run[r] = mnew;
            #pragma unroll
            for (int ct = 0; ct < 8; ++ct) acc[ct][r] *= scale;
        }
        #pragma unroll
        for (int jj = 0; jj < 2; ++jj) {
            const int jt = 2 * chalf + jj;
            #pragma unroll
            for (int r = 0; r < 4; ++r) {
                const int row = slab * 16 + 4 * hi + r;
                int byte = row * 128 + (jt * 16 + lo) * 2;
                byte ^= ((row & 7) << 4);
                *(f16*)((char*)p_lds + byte) = (f16)p[jt][r];
            }
        }
        __syncthreads();
        #pragma unroll
        for (int ksplit = 0; ksplit < 2; ++ksplit) {
            const int row = slab * 16 + lo;
            int byte = row * 128 + (ksplit * 32 + 8 * hi) * 2;
            byte ^= ((row & 7) << 4);
            const half8 pfrag = *(const half8*)((const char*)p_lds + byte);
            #pragma unroll
            for (int ct = 0; ct < 8; ++ct) {
                const int c = chalf * 128 + ct * 16 + lo;
                const half8 vfrag = *(const half8*)(vbase + (size_t)c * NPOS + j0 + ksplit * 32 + 8 * hi);
                acc[ct] = __builtin_amdgcn_mfma_f32_16x16x32_f16(pfrag, vfrag, acc[ct], 0, 0, 0);
            }
        }
        __syncthreads();
    }

    const float gamma = gamp[0];
    #pragma unroll
    for (int ct = 0; ct < 8; ++ct) {
        const int c = chalf * 128 + ct * 16 + lo;
        #pragma unroll
        for (int r = 0; r < 4; ++r) {
            const int n = q0 + slab * 16 + 4 * hi + r;
            const size_t idx = ((size_t)b * CCH + c) * NPOS + n;
            const float o = acc[ct][r] / l_run[r];
            if (add_residual) {
                const float val = gamma * o + xres[idx];
                out_h[idx] = (f16)val;
                out_f[idx] = val;
            } else {
                out_h[idx] = (f16)o;
            }
        }
    }
}

// ---------------------------------------------------------------------------
// Per-(b,c) row: unbiased variance of sw_bg and of mask*x1, then
// out = x1 + gamma*(mask*x1)*sqrt((var_g+eps)/(var_f+eps)). grid (C,B).
// Output dtype chosen at runtime from mask_raw sniff.
// ---------------------------------------------------------------------------
__global__ __launch_bounds__(256) void fmm_final(
    const float* __restrict__ x1f,   // (B,C,N)
    const f16*  __restrict__ bg,     // (B,C,N)
    const float* __restrict__ maskf, // (B,N)
    const float* __restrict__ gamp,
    const uint32_t* __restrict__ mask_raw,
    void* __restrict__ outp)         // (B,C,N) bf16 or f32
{
    const bool bf = detect_bf16(mask_raw);
    const int b = blockIdx.y;
    const int c = blockIdx.x;
    const int tid = threadIdx.x;
    const size_t rowoff = ((size_t)b * CCH + c) * NPOS;
    const float* xrow = x1f + rowoff;
    const f16*  grow = bg + rowoff;
    const float* mrow = maskf + (size_t)b * NPOS;

    float s_f = 0.f, ss_f = 0.f, s_g = 0.f, ss_g = 0.f;
    #pragma unroll
    for (int u = 0; u < 2; ++u) {
        const int i = tid * 16 + u * 8;
        const float4 x0 = *(const float4*)(xrow + i);
        const float4 x1v = *(const float4*)(xrow + i + 4);
        const float4 m0 = *(const float4*)(mrow + i);
        const float4 m1 = *(const float4*)(mrow + i + 4);
        half8 gv = *(const half8*)(grow + i);
        const float xs[8] = {x0.x, x0.y, x0.z, x0.w, x1v.x, x1v.y, x1v.z, x1v.w};
        const float ms[8] = {m0.x, m0.y, m0.z, m0.w, m1.x, m1.y, m1.z, m1.w};
        #pragma unroll
        for (int j = 0; j < 8; ++j) {
            const float f = xs[j] * ms[j];
            const float g = (float)gv[j];
            s_f += f; ss_f += f * f;
            s_g += g; ss_g += g * g;
        }
    }
    #pragma unroll
    for (int off = 1; off < 64; off <<= 1) {
        s_f += __shfl_xor(s_f, off, 64);
        ss_f += __shfl_xor(ss_f, off, 64);
        s_g += __shfl_xor(s_g, off, 64);
        ss_g += __shfl_xor(ss_g, off, 64);
    }
    __shared__ float red[4][4];
    const int wv_ = tid >> 6;
    if ((tid & 63) == 0) {
        red[wv_][0] = s_f; red[wv_][1] = ss_f; red[wv_][2] = s_g; red[wv_][3] = ss_g;
    }
    __syncthreads();
    s_f  = red[0][0] + red[1][0] + red[2][0] + red[3][0];
    ss_f = red[0][1] + red[1][1] + red[2][1] + red[3][1];
    s_g  = red[0][2] + red[1][2] + red[2][2] + red[3][2];
    ss_g = red[0][3] + red[1][3] + red[2][3] + red[3][3];

    const float nn = 4096.f, nm1 = 4095.f;
    const float var_f = (ss_f - s_f * s_f / nn) / nm1;
    const float var_g = (ss_g - s_g * s_g / nn) / nm1;
    const float ratio = sqrtf((var_g + 1e-5f) / (var_f + 1e-5f));
    const float gamma = gamp[0];

    #pragma unroll
    for (int u = 0; u < 2; ++u) {
        const int i = tid * 16 + u * 8;
        const float4 x0 = *(const float4*)(xrow + i);
        const float4 x1v = *(const float4*)(xrow + i + 4);
        const float4 m0 = *(const float4*)(mrow + i);
        const float4 m1 = *(const float4*)(mrow + i + 4);
        const float xs[8] = {x0.x, x0.y, x0.z, x0.w, x1v.x, x1v.y, x1v.z, x1v.w};
        const float ms[8] = {m0.x, m0.y, m0.z, m0.w, m1.x, m1.y, m1.z, m1.w};
        float ov[8];
        #pragma unroll
        for (int j = 0; j < 8; ++j)
            ov[j] = xs[j] + gamma * (xs[j] * ms[j]) * ratio;
        if (bf) {
            short8 sv;
            #pragma unroll
            for (int j = 0; j < 8; ++j) sv[j] = f2bf(ov[j]);
            *(short8*)((short*)outp + rowoff + i) = sv;
        } else {
            float4 f0 = {ov[0], ov[1], ov[2], ov[3]}, f1 = {ov[4], ov[5], ov[6], ov[7]};
            *(float4*)((float*)outp + rowoff + i) = f0;
            *(float4*)((float*)outp + rowoff + i + 4) = f1;
        }
    }
}

// ---------------------------------------------------------------------------
// ws map (bytes): qk[0,1M) v[1M,5M) x1h[5M,9M) bg[9M,13M) x1f[13M,21M)
//   xh[21M,25M) xf[25M,33M) maskf@33M gam@33M+32K w1qk@33M+64K w1v@33M+96K
//   b1@33M+224K w2qk@33M+226K w2v@33M+258K b2@33M+386K   (~33.4 MB total)
// ---------------------------------------------------------------------------
extern "C" void kernel_launch(void* const* d_in, const int* in_sizes, int n_in,
                              void* d_out, int out_size, void* d_ws, size_t ws_size,
                              hipStream_t stream)
{
    const size_t MB = 1u << 20, KB = 1u << 10;
    char* ws = (char*)d_ws;
    f16*   qkbuf = (f16*)(ws);
    f16*   vbuf  = (f16*)(ws + 1 * MB);
    f16*   x1h   = (f16*)(ws + 5 * MB);
    f16*   bgbuf = (f16*)(ws + 9 * MB);
    float* x1f   = (float*)(ws + 13 * MB);
    f16*   xh    = (f16*)(ws + 21 * MB);
    float* xf    = (float*)(ws + 25 * MB);
    float* maskf = (float*)(ws + 33 * MB);
    float* gam   = (float*)(ws + 33 * MB + 32 * KB);
    f16*   w1qk  = (f16*)(ws + 33 * MB + 64 * KB);
    f16*   w1v   = (f16*)(ws + 33 * MB + 96 * KB);
    f16*   b1    = (f16*)(ws + 33 * MB + 224 * KB);
    f16*   w2qk  = (f16*)(ws + 33 * MB + 226 * KB);
    f16*   w2v   = (f16*)(ws + 33 * MB + 258 * KB);
    f16*   b2    = (f16*)(ws + 33 * MB + 386 * KB);

    dim3 blk(256);
    dim3 vgrid(1109);
    dim3 cgrid(NPOS / 64, BATCH);
    dim3 agrid(NPOS / 32, BATCH);
    dim3 fgrid(CCH, BATCH);

    convert_inputs<<<vgrid, blk, 0, stream>>>(
        d_in[0], (const uint32_t*)d_in[1],
        d_in[2], d_in[4], d_in[6], d_in[3], d_in[5], d_in[7], d_in[8],
        d_in[9], d_in[11], d_in[13], d_in[10], d_in[12], d_in[14], d_in[15],
        xh, xf, maskf, w1qk, w1v, b1, w2qk, w2v, b2, gam);

    // self-attention: x1 = sa_gamma * attn(x) + x
    conv_qkv<<<cgrid, blk, 0, stream>>>(xh, w1qk, w1v, b1, maskf, 0, qkbuf, vbuf);
    attn_fused<<<agrid, blk, 0, stream>>>(qkbuf, vbuf, xf, gam + 0, x1h, x1f, 1);
    // masked cross-attention: bg = attn(mask*x1 -> q; (1-mask)*x1 -> k,v)
    conv_qkv<<<cgrid, blk, 0, stream>>>(x1h, w2qk, w2v, b2, maskf, 1, qkbuf, vbuf);
    attn_fused<<<agrid, blk, 0, stream>>>(qkbuf, vbuf, xf, gam + 1, bgbuf, nullptr, 0);
    // FMM epilogue
    fmm_final<<<fgrid, blk, 0, stream>>>(x1f, bgbuf, maskf, gam + 1,
                                         (const uint32_t*)d_in[1], d_out);
}

// Round 3
// 361.435 us; speedup vs baseline: 1.4764x; 1.4764x over previous
//
#include <hip/hip_runtime.h>
#include <stdint.h>

typedef _Float16 f16;
typedef __attribute__((ext_vector_type(8))) _Float16 half8;
typedef __attribute__((ext_vector_type(4))) _Float16 half4;
typedef __attribute__((ext_vector_type(8))) short short8;
typedef __attribute__((ext_vector_type(4))) float f32x4;

#define NPOS 4096
#define CCH  256
#define OQK  64
#define BATCH 2
#define NSPLIT 4
#define KEYS_PER_SPLIT 1024

__device__ __forceinline__ float bf2f(short u) {
    union { uint32_t i; float f; } c;
    c.i = ((uint32_t)(uint16_t)u) << 16;
    return c.f;
}
__device__ __forceinline__ short f2bf(float f) {
    union { float f; uint32_t i; } c; c.f = f;
    uint32_t lsb = (c.i >> 16) & 1u;
    c.i += 0x7FFFu + lsb;
    return (short)(c.i >> 16);
}

// Deterministic dtype sniff: mask values are exactly {0.0,1.0}.
// fp32 words: low16 always 0x0000. bf16 pairs: low16 in {0x0000,0x3F80}.
__device__ __forceinline__ bool detect_bf16(const uint32_t* mw) {
    int hits = 0;
    #pragma unroll
    for (int i = 0; i < 64; ++i) hits += ((mw[i] & 0xFFFFu) == 0x3F80u) ? 1 : 0;
    return hits != 0;
}

__device__ __forceinline__ void load8(const void* base, size_t e0, bool bf, float* v) {
    if (bf) {
        short8 s = *(const short8*)((const short*)base + e0);
        #pragma unroll
        for (int j = 0; j < 8; ++j) v[j] = bf2f(s[j]);
    } else {
        const float* fp = (const float*)base + e0;
        float4 a = *(const float4*)fp;
        float4 b = *(const float4*)(fp + 4);
        v[0] = a.x; v[1] = a.y; v[2] = a.z; v[3] = a.w;
        v[4] = b.x; v[5] = b.y; v[6] = b.z; v[7] = b.w;
    }
}
__device__ __forceinline__ float load1(const void* base, int i, bool bf) {
    return bf ? bf2f(((const short*)base)[i]) : ((const float*)base)[i];
}

// ---------------------------------------------------------------------------
// Canonicalize small inputs: mask -> maskf f32; weights -> f16 packed
// (wqk (64,256): rows 0-31 q, 32-63 k; wv (256,256)); biases f16[320]; gam f32[2].
// grid = 85 blocks x 256.
// ---------------------------------------------------------------------------
__global__ __launch_bounds__(256) void convert_inputs(
    const uint32_t* __restrict__ mask_raw,
    const void* __restrict__ w1q, const void* __restrict__ w1k, const void* __restrict__ w1v_,
    const void* __restrict__ b1q, const void* __restrict__ b1k, const void* __restrict__ b1v_,
    const void* __restrict__ g1,
    const void* __restrict__ w2q, const void* __restrict__ w2k, const void* __restrict__ w2v_,
    const void* __restrict__ b2q, const void* __restrict__ b2k, const void* __restrict__ b2v_,
    const void* __restrict__ g2,
    float* __restrict__ maskf,
    f16* __restrict__ w1qk, f16* __restrict__ w1vm, f16* __restrict__ b1,
    f16* __restrict__ w2qk, f16* __restrict__ w2vm, f16* __restrict__ b2,
    float* __restrict__ gam)
{
    const bool bf = detect_bf16(mask_raw);
    const int blk = blockIdx.x, tid = threadIdx.x;
    float v[8];
    if (blk < 4) {                          // mask: 8192
        const size_t e0 = ((size_t)blk * 256 + tid) * 8;
        load8(mask_raw, e0, bf, v);
        float4 f0 = {v[0], v[1], v[2], v[3]}, f1 = {v[4], v[5], v[6], v[7]};
        *(float4*)(maskf + e0) = f0;
        *(float4*)(maskf + e0 + 4) = f1;
    } else if (blk < 12) {                  // w1qk: 16384
        const size_t g = ((size_t)(blk - 4) * 256 + tid) * 8;
        const int o = (int)(g >> 8), cc = (int)(g & 255);
        const void* src = (o < 32) ? w1q : w1k;
        const size_t se = (size_t)((o < 32) ? o : o - 32) * 256 + cc;
        load8(src, se, bf, v);
        half8 h;
        #pragma unroll
        for (int j = 0; j < 8; ++j) h[j] = (f16)v[j];
        *(half8*)(w1qk + g) = h;
    } else if (blk < 44) {                  // w1v: 65536
        const size_t g = ((size_t)(blk - 12) * 256 + tid) * 8;
        load8(w1v_, g, bf, v);
        half8 h;
        #pragma unroll
        for (int j = 0; j < 8; ++j) h[j] = (f16)v[j];
        *(half8*)(w1vm + g) = h;
    } else if (blk < 52) {                  // w2qk
        const size_t g = ((size_t)(blk - 44) * 256 + tid) * 8;
        const int o = (int)(g >> 8), cc = (int)(g & 255);
        const void* src = (o < 32) ? w2q : w2k;
        const size_t se = (size_t)((o < 32) ? o : o - 32) * 256 + cc;
        load8(src, se, bf, v);
        half8 h;
        #pragma unroll
        for (int j = 0; j < 8; ++j) h[j] = (f16)v[j];
        *(half8*)(w2qk + g) = h;
    } else if (blk < 84) {                  // w2v
        const size_t g = ((size_t)(blk - 52) * 256 + tid) * 8;
        load8(w2v_, g, bf, v);
        half8 h;
        #pragma unroll
        for (int j = 0; j < 8; ++j) h[j] = (f16)v[j];
        *(half8*)(w2vm + g) = h;
    } else {                                // biases + gammas
        for (int i = tid; i < 320; i += 256) {
            const void* s1 = (i < 32) ? b1q : (i < 64) ? b1k : b1v_;
            const void* s2 = (i < 32) ? b2q : (i < 64) ? b2k : b2v_;
            const int ii = (i < 32) ? i : (i < 64) ? i - 32 : i - 64;
            b1[i] = (f16)load1(s1, ii, bf);
            b2[i] = (f16)load1(s2, ii, bf);
        }
        if (tid == 0) {
            gam[0] = load1(g1, 0, bf);
            gam[1] = load1(g2, 0, bf);
        }
    }
}

// ---------------------------------------------------------------------------
// Fused 1x1 conv: q,k packed (B,N,64); v (B,C,N); f16 out.
// xin: is_raw=1 -> raw x (dtype sniffed), else f32 (x1f).
// use_mask: q *= mask[n], k/v *= (1-mask[n]); bias unmasked (linearity).
// grid (N/64, B), 256 threads. LDS x-tile [n][c] XOR-swizzled.
// ---------------------------------------------------------------------------
__global__ __launch_bounds__(256) void conv_qkv(
    const void* __restrict__ xin, int is_raw,
    const uint32_t* __restrict__ mask_raw,
    const f16* __restrict__ wqk,
    const f16* __restrict__ wvm,
    const f16* __restrict__ bias,
    const float* __restrict__ maskf, int use_mask,
    f16* __restrict__ qkout,
    f16* __restrict__ vout)
{
    const bool bf = is_raw ? detect_bf16(mask_raw) : false;
    const int b    = blockIdx.y;
    const int n0   = blockIdx.x * 64;
    const int tid  = threadIdx.x;
    const int lane = tid & 63;
    const int w    = tid >> 6;
    const int lo   = lane & 15;
    const int hi   = lane >> 4;

    __shared__ f16 xt[64 * 256];   // [n][c], 32 KB

    {
        const int nc = tid & 7;
        const int cg = tid >> 3;
        #pragma unroll
        for (int it = 0; it < 8; ++it) {
            const int c = cg + 32 * it;
            const size_t off = ((size_t)b * CCH + c) * NPOS + n0 + nc * 8;
            float v8[8];
            load8(xin, off, bf, v8);
            #pragma unroll
            for (int j = 0; j < 8; ++j) {
                const int n = nc * 8 + j;
                int byte = n * 512 + c * 2;
                byte ^= ((n & 7) << 4);
                *(f16*)((char*)xt + byte) = (f16)v8[j];
            }
        }
    }
    __syncthreads();

    const f32x4 z = {0.f, 0.f, 0.f, 0.f};
    f32x4 acc_qk[4];
    f32x4 acc_v[4][4];
    #pragma unroll
    for (int i = 0; i < 4; ++i) {
        acc_qk[i] = z;
        #pragma unroll
        for (int j = 0; j < 4; ++j) acc_v[i][j] = z;
    }

    #pragma unroll 1
    for (int ks = 0; ks < 8; ++ks) {
        const int ce = ks * 32 + 8 * hi;
        half8 xfr[4];
        #pragma unroll
        for (int nt = 0; nt < 4; ++nt) {
            const int n = nt * 16 + lo;
            int byte = n * 512 + ce * 2;
            byte ^= ((n & 7) << 4);
            xfr[nt] = *(const half8*)((const char*)xt + byte);
        }
        {
            half8 wf = *(const half8*)(wqk + (size_t)(w * 16 + lo) * 256 + ce);
            #pragma unroll
            for (int nt = 0; nt < 4; ++nt)
                acc_qk[nt] = __builtin_amdgcn_mfma_f32_16x16x32_f16(xfr[nt], wf, acc_qk[nt], 0, 0, 0);
        }
        #pragma unroll
        for (int ot = 0; ot < 4; ++ot) {
            half8 wf = *(const half8*)(wvm + (size_t)(w * 64 + ot * 16 + lo) * 256 + ce);
            #pragma unroll
            for (int nt = 0; nt < 4; ++nt)
                acc_v[ot][nt] = __builtin_amdgcn_mfma_f32_16x16x32_f16(wf, xfr[nt], acc_v[ot][nt], 0, 0, 0);
        }
    }

    {   // qk epilogue: col o = w*16+lo, rows n = nt*16 + 4*hi + r
        const int o = w * 16 + lo;
        const float bb = (float)bias[o];
        #pragma unroll
        for (int nt = 0; nt < 4; ++nt) {
            #pragma unroll
            for (int r = 0; r < 4; ++r) {
                const int n = n0 + nt * 16 + 4 * hi + r;
                float mult = 1.f;
                if (use_mask) {
                    const float mv = maskf[b * NPOS + n];
                    mult = (o < 32) ? mv : (1.f - mv);
                }
                qkout[((size_t)b * NPOS + n) * OQK + o] = (f16)(mult * acc_qk[nt][r] + bb);
            }
        }
    }
    {   // v epilogue: col n = nt*16+lo, rows o = w*64 + ot*16 + 4*hi + r
        float mv_n[4];
        #pragma unroll
        for (int nt = 0; nt < 4; ++nt)
            mv_n[nt] = use_mask ? (1.f - maskf[b * NPOS + n0 + nt * 16 + lo]) : 1.f;
        #pragma unroll
        for (int ot = 0; ot < 4; ++ot) {
            #pragma unroll
            for (int r = 0; r < 4; ++r) {
                const int oc = w * 64 + ot * 16 + 4 * hi + r;
                const float bb = (float)bias[64 + oc];
                #pragma unroll
                for (int nt = 0; nt < 4; ++nt) {
                    const int n = n0 + nt * 16 + lo;
                    vout[((size_t)b * CCH + oc) * NPOS + n] = (f16)(mv_n[nt] * acc_v[ot][nt][r] + bb);
                }
            }
        }
    }
}

// ---------------------------------------------------------------------------
// Split-KV flash attention. grid (N/64, NSPLIT, B), 256 threads = 4 waves.
// Each wave owns 16 q-rows (full 256 channels) and a PRIVATE 2KB LDS P-buffer
// -> no __syncthreads anywhere; P transpose is wave-internal (lgkmcnt only).
// Defer-max (THR=8) skips rescale on most tiles. Writes per-split normalized
// O (f16) + (m,l) (f32) partials; attn_merge combines.
// ---------------------------------------------------------------------------
__global__ __launch_bounds__(256) void attn_split(
    const f16* __restrict__ qk,      // (B,N,64)
    const f16* __restrict__ vbuf,    // (B,C,N)
    f16* __restrict__ po,            // (NSPLIT,B,C,N)
    float2* __restrict__ pml)        // (NSPLIT,B,N)
{
    const int b     = blockIdx.z;
    const int split = blockIdx.y;
    const int tid   = threadIdx.x;
    const int lane  = tid & 63;
    const int w     = tid >> 6;
    const int lo    = lane & 15;
    const int hi    = lane >> 4;
    const int qrow0 = blockIdx.x * 64 + w * 16;

    __shared__ f16 p_lds[4][16 * 64];
    char* pbase = (char*)p_lds[w];

    const half8 qfrag = *(const half8*)(qk + ((size_t)b * NPOS + qrow0 + lo) * OQK + 8 * hi);
    const f16* kbase = qk + (size_t)b * NPOS * OQK + 32 + 8 * hi;
    const f16* vbase = vbuf + (size_t)b * CCH * NPOS + 8 * hi;

    const f32x4 z = {0.f, 0.f, 0.f, 0.f};
    f32x4 acc[16];
    #pragma unroll
    for (int i = 0; i < 16; ++i) acc[i] = z;
    float m_run[4], l_run[4];
    #pragma unroll
    for (int r = 0; r < 4; ++r) { m_run[r] = -3.0e38f; l_run[r] = 0.f; }

    #pragma unroll 1
    for (int kt = 0; kt < KEYS_PER_SPLIT / 64; ++kt) {
        const int j0 = split * KEYS_PER_SPLIT + kt * 64;
        f32x4 s[4];
        #pragma unroll
        for (int jt = 0; jt < 4; ++jt) {
            const half8 kfrag = *(const half8*)(kbase + (size_t)(j0 + jt * 16 + lo) * OQK);
            s[jt] = __builtin_amdgcn_mfma_f32_16x16x32_f16(qfrag, kfrag, z, 0, 0, 0);
        }
        // row maxima (rows i = 4*hi + r), reduce over 16 lo-lanes
        float pm[4];
        #pragma unroll
        for (int r = 0; r < 4; ++r)
            pm[r] = fmaxf(fmaxf(s[0][r], s[1][r]), fmaxf(s[2][r], s[3][r]));
        #pragma unroll
        for (int off = 1; off < 16; off <<= 1) {
            #pragma unroll
            for (int r = 0; r < 4; ++r)
                pm[r] = fmaxf(pm[r], __shfl_xor(pm[r], off, 64));
        }
        const float grow = fmaxf(fmaxf(pm[0] - m_run[0], pm[1] - m_run[1]),
                                 fmaxf(pm[2] - m_run[2], pm[3] - m_run[3]));
        if (__any(grow > 8.f)) {     // defer-max: rescale only on real growth
            #pragma unroll
            for (int r = 0; r < 4; ++r) {
                const float mnew = fmaxf(m_run[r], pm[r]);
                const float sc = __expf(m_run[r] - mnew);
                m_run[r] = mnew;
                l_run[r] *= sc;
                #pragma unroll
                for (int ct = 0; ct < 16; ++ct) acc[ct][r] *= sc;
            }
        }
        float rs[4];
        #pragma unroll
        for (int r = 0; r < 4; ++r) {
            rs[r] = 0.f;
            #pragma unroll
            for (int jt = 0; jt < 4; ++jt) {
                const float pv = __expf(s[jt][r] - m_run[r]);
                s[jt][r] = pv;
                rs[r] += pv;
            }
        }
        #pragma unroll
        for (int off = 1; off < 16; off <<= 1) {
            #pragma unroll
            for (int r = 0; r < 4; ++r)
                rs[r] += __shfl_xor(rs[r], off, 64);
        }
        #pragma unroll
        for (int r = 0; r < 4; ++r) l_run[r] += rs[r];

        // P -> private LDS (wave-internal transpose), swizzled
        #pragma unroll
        for (int jt = 0; jt < 4; ++jt) {
            #pragma unroll
            for (int r = 0; r < 4; ++r) {
                const int row = 4 * hi + r;
                int byte = row * 128 + (jt * 16 + lo) * 2;
                byte ^= ((row & 7) << 4);
                *(f16*)(pbase + byte) = (f16)s[jt][r];
            }
        }
        asm volatile("s_waitcnt lgkmcnt(0)" ::: "memory");
        __builtin_amdgcn_sched_barrier(0);
        #pragma unroll
        for (int ksp = 0; ksp < 2; ++ksp) {
            int byte = lo * 128 + (ksp * 32 + 8 * hi) * 2;
            byte ^= ((lo & 7) << 4);
            const half8 pfrag = *(const half8*)(pbase + byte);
            #pragma unroll
            for (int ct = 0; ct < 16; ++ct) {
                const half8 vfrag = *(const half8*)(vbase + (size_t)(ct * 16 + lo) * NPOS + j0 + ksp * 32);
                acc[ct] = __builtin_amdgcn_mfma_f32_16x16x32_f16(pfrag, vfrag, acc[ct], 0, 0, 0);
            }
        }
    }

    float inv_l[4];
    #pragma unroll
    for (int r = 0; r < 4; ++r) inv_l[r] = 1.f / l_run[r];
    const size_t pobase = (((size_t)split * BATCH + b) * CCH) * NPOS;
    #pragma unroll
    for (int ct = 0; ct < 16; ++ct) {
        const int c = ct * 16 + lo;
        half4 o4;
        #pragma unroll
        for (int r = 0; r < 4; ++r) o4[r] = (f16)(acc[ct][r] * inv_l[r]);
        *(half4*)(po + pobase + (size_t)c * NPOS + qrow0 + 4 * hi) = o4;
    }
    if (lo == 0) {
        #pragma unroll
        for (int r = 0; r < 4; ++r) {
            const int n = qrow0 + 4 * hi + r;
            float2 v; v.x = m_run[r]; v.y = l_run[r];
            pml[((size_t)split * BATCH + b) * NPOS + n] = v;
        }
    }
}

// ---------------------------------------------------------------------------
// Merge NSPLIT partials: O = sum_s w_s*o_s / sum_s w_s, w_s = e^{m_s-M} l_s.
// Pass1 (add_residual): out_f = gamma*O + x (raw dtype). Pass2: out_h = O.
// grid (N/32, B), 256 threads: tid&31 -> n, tid>>5 -> c-group of 32.
// ---------------------------------------------------------------------------
__global__ __launch_bounds__(256) void attn_merge(
    const f16* __restrict__ po,
    const float2* __restrict__ pml,
    const void* __restrict__ xraw,
    const uint32_t* __restrict__ mask_raw,
    const float* __restrict__ gamp,
    float* __restrict__ out_f,
    f16* __restrict__ out_h,
    int add_residual)
{
    const int b = blockIdx.y;
    const int n = blockIdx.x * 32 + (threadIdx.x & 31);
    const int cg = threadIdx.x >> 5;
    float m[NSPLIT], l[NSPLIT];
    #pragma unroll
    for (int s = 0; s < NSPLIT; ++s) {
        float2 v = pml[((size_t)s * BATCH + b) * NPOS + n];
        m[s] = v.x; l[s] = v.y;
    }
    float M = m[0];
    #pragma unroll
    for (int s = 1; s < NSPLIT; ++s) M = fmaxf(M, m[s]);
    float wgt[NSPLIT], wsum = 0.f;
    #pragma unroll
    for (int s = 0; s < NSPLIT; ++s) { wgt[s] = __expf(m[s] - M) * l[s]; wsum += wgt[s]; }
    const float winv = 1.f / wsum;
    #pragma unroll
    for (int s = 0; s < NSPLIT; ++s) wgt[s] *= winv;

    const float gamma = gamp[0];
    const bool bf = add_residual ? detect_bf16(mask_raw) : false;
    #pragma unroll 4
    for (int i = 0; i < 32; ++i) {
        const int c = cg * 32 + i;
        const size_t base = ((size_t)b * CCH + c) * NPOS + n;
        float o = 0.f;
        #pragma unroll
        for (int s = 0; s < NSPLIT; ++s)
            o += wgt[s] * (float)po[(((size_t)s * BATCH + b) * CCH + c) * NPOS + n];
        if (add_residual) {
            const float xr = bf ? bf2f(((const short*)xraw)[base]) : ((const float*)xraw)[base];
            out_f[base] = gamma * o + xr;
        } else {
            out_h[base] = (f16)o;
        }
    }
}

// ---------------------------------------------------------------------------
// Per-(b,c) row: unbiased variance of bg and of mask*x1;
// out = x1 + gamma*(mask*x1)*sqrt((var_g+eps)/(var_f+eps)). grid (C,B).
// Output dtype (bf16/f32) chosen at runtime from mask_raw sniff.
// ---------------------------------------------------------------------------
__global__ __launch_bounds__(256) void fmm_final(
    const float* __restrict__ x1f,
    const f16*  __restrict__ bg,
    const float* __restrict__ maskf,
    const float* __restrict__ gamp,
    const uint32_t* __restrict__ mask_raw,
    void* __restrict__ outp)
{
    const bool bf = detect_bf16(mask_raw);
    const int b = blockIdx.y;
    const int c = blockIdx.x;
    const int tid = threadIdx.x;
    const size_t rowoff = ((size_t)b * CCH + c) * NPOS;
    const float* xrow = x1f + rowoff;
    const f16*  grow = bg + rowoff;
    const float* mrow = maskf + (size_t)b * NPOS;

    float s_f = 0.f, ss_f = 0.f, s_g = 0.f, ss_g = 0.f;
    #pragma unroll
    for (int u = 0; u < 2; ++u) {
        const int i = tid * 16 + u * 8;
        const float4 x0 = *(const float4*)(xrow + i);
        const float4 x1v = *(const float4*)(xrow + i + 4);
        const float4 m0 = *(const float4*)(mrow + i);
        const float4 m1 = *(const float4*)(mrow + i + 4);
        half8 gv = *(const half8*)(grow + i);
        const float xs[8] = {x0.x, x0.y, x0.z, x0.w, x1v.x, x1v.y, x1v.z, x1v.w};
        const float ms[8] = {m0.x, m0.y, m0.z, m0.w, m1.x, m1.y, m1.z, m1.w};
        #pragma unroll
        for (int j = 0; j < 8; ++j) {
            const float f = xs[j] * ms[j];
            const float g = (float)gv[j];
            s_f += f; ss_f += f * f;
            s_g += g; ss_g += g * g;
        }
    }
    #pragma unroll
    for (int off = 1; off < 64; off <<= 1) {
        s_f += __shfl_xor(s_f, off, 64);
        ss_f += __shfl_xor(ss_f, off, 64);
        s_g += __shfl_xor(s_g, off, 64);
        ss_g += __shfl_xor(ss_g, off, 64);
    }
    __shared__ float red[4][4];
    const int wv_ = tid >> 6;
    if ((tid & 63) == 0) {
        red[wv_][0] = s_f; red[wv_][1] = ss_f; red[wv_][2] = s_g; red[wv_][3] = ss_g;
    }
    __syncthreads();
    s_f  = red[0][0] + red[1][0] + red[2][0] + red[3][0];
    ss_f = red[0][1] + red[1][1] + red[2][1] + red[3][1];
    s_g  = red[0][2] + red[1][2] + red[2][2] + red[3][2];
    ss_g = red[0][3] + red[1][3] + red[2][3] + red[3][3];

    const float nn = 4096.f, nm1 = 4095.f;
    const float var_f = (ss_f - s_f * s_f / nn) / nm1;
    const float var_g = (ss_g - s_g * s_g / nn) / nm1;
    const float ratio = sqrtf((var_g + 1e-5f) / (var_f + 1e-5f));
    const float gamma = gamp[0];

    #pragma unroll
    for (int u = 0; u < 2; ++u) {
        const int i = tid * 16 + u * 8;
        const float4 x0 = *(const float4*)(xrow + i);
        const float4 x1v = *(const float4*)(xrow + i + 4);
        const float4 m0 = *(const float4*)(mrow + i);
        const float4 m1 = *(const float4*)(mrow + i + 4);
        const float xs[8] = {x0.x, x0.y, x0.z, x0.w, x1v.x, x1v.y, x1v.z, x1v.w};
        const float ms[8] = {m0.x, m0.y, m0.z, m0.w, m1.x, m1.y, m1.z, m1.w};
        float ov[8];
        #pragma unroll
        for (int j = 0; j < 8; ++j)
            ov[j] = xs[j] + gamma * (xs[j] * ms[j]) * ratio;
        if (bf) {
            short8 sv;
            #pragma unroll
            for (int j = 0; j < 8; ++j) sv[j] = f2bf(ov[j]);
            *(short8*)((short*)outp + rowoff + i) = sv;
        } else {
            float4 f0 = {ov[0], ov[1], ov[2], ov[3]}, f1 = {ov[4], ov[5], ov[6], ov[7]};
            *(float4*)((float*)outp + rowoff + i) = f0;
            *(float4*)((float*)outp + rowoff + i + 4) = f1;
        }
    }
}

// ---------------------------------------------------------------------------
// ws map: qk[0,1M) v[1M,5M) | bg[0,4M) after attn2 | x1f[5M,13M)
//   po[13M,29M) pml[29M,+256K) maskf@29M+512K w*@30M  (~30.4 MB total)
// ---------------------------------------------------------------------------
extern "C" void kernel_launch(void* const* d_in, const int* in_sizes, int n_in,
                              void* d_out, int out_size, void* d_ws, size_t ws_size,
                              hipStream_t stream)
{
    const size_t MB = 1u << 20, KB = 1u << 10;
    char* ws = (char*)d_ws;
    f16*    qkbuf = (f16*)(ws);
    f16*    vbuf  = (f16*)(ws + 1 * MB);
    f16*    bgbuf = (f16*)(ws);             // overlaps qk/v; written after attn2
    float*  x1f   = (float*)(ws + 5 * MB);
    f16*    po    = (f16*)(ws + 13 * MB);
    float2* pml   = (float2*)(ws + 29 * MB);
    float*  maskf = (float*)(ws + 29 * MB + 512 * KB);
    f16*    w1qk  = (f16*)(ws + 30 * MB);
    f16*    w1v   = (f16*)(ws + 30 * MB + 32 * KB);
    f16*    b1    = (f16*)(ws + 30 * MB + 160 * KB);
    f16*    w2qk  = (f16*)(ws + 30 * MB + 164 * KB);
    f16*    w2v   = (f16*)(ws + 30 * MB + 196 * KB);
    f16*    b2    = (f16*)(ws + 30 * MB + 324 * KB);
    float*  gam   = (float*)(ws + 30 * MB + 328 * KB);

    const uint32_t* mraw = (const uint32_t*)d_in[1];

    dim3 blk(256);
    dim3 vgrid(85);
    dim3 cgrid(NPOS / 64, BATCH);
    dim3 agrid(NPOS / 64, NSPLIT, BATCH);
    dim3 mgrid(NPOS / 32, BATCH);
    dim3 fgrid(CCH, BATCH);

    convert_inputs<<<vgrid, blk, 0, stream>>>(
        mraw,
        d_in[2], d_in[4], d_in[6], d_in[3], d_in[5], d_in[7], d_in[8],
        d_in[9], d_in[11], d_in[13], d_in[10], d_in[12], d_in[14], d_in[15],
        maskf, w1qk, w1v, b1, w2qk, w2v, b2, gam);

    // pass 1: x1 = sa_gamma * attn(x) + x   (x1f f32)
    conv_qkv<<<cgrid, blk, 0, stream>>>(d_in[0], 1, mraw, w1qk, w1v, b1, maskf, 0, qkbuf, vbuf);
    attn_split<<<agrid, blk, 0, stream>>>(qkbuf, vbuf, po, pml);
    attn_merge<<<mgrid, blk, 0, stream>>>(po, pml, d_in[0], mraw, gam + 0, x1f, nullptr, 1);
    // pass 2: bg = attn(mask*x1 -> q; (1-mask)*x1 -> k,v)
    conv_qkv<<<cgrid, blk, 0, stream>>>(x1f, 0, mraw, w2qk, w2v, b2, maskf, 1, qkbuf, vbuf);
    attn_split<<<agrid, blk, 0, stream>>>(qkbuf, vbuf, po, pml);
    attn_merge<<<mgrid, blk, 0, stream>>>(po, pml, nullptr, mraw, gam + 1, nullptr, bgbuf, 0);
    // FMM epilogue
    fmm_final<<<fgrid, blk, 0, stream>>>(x1f, bgbuf, maskf, gam + 1, mraw, d_out);
}